// Round 19
// baseline (1754.697 us; speedup 1.0000x reference)
//
#include <hip/hip_runtime.h>
#include <hip/hip_bf16.h>
#include <math.h>

#define DEV __device__ __forceinline__

typedef unsigned short u16;
typedef short bf16x8 __attribute__((ext_vector_type(8)));
typedef float f32x4 __attribute__((ext_vector_type(4)));
typedef u16 u16x8 __attribute__((ext_vector_type(8)));
typedef u16 u16x4 __attribute__((ext_vector_type(4)));

#define T_SEQ 1024
#define NTOK 2048
#define DIM 1024
#define NHD 16
#define NKVH 8
#define HDIM 64
#define KVD 512
#define MLPD 3072
#define VOC 32768
#define EPSF 1.1920929e-07f
#define SCAP 30.0f
#define NCB 512   // 32768 / 64 col-blocks for LM-head partial LSE
#define PSTRIDE ((size_t)NTOK * DIM)

#define MEMFENCE asm volatile("" ::: "memory")

DEV u16 f2b(float f) {
  __hip_bfloat16 h = __float2bfloat16(f);
  u16 r; __builtin_memcpy(&r, &h, 2); return r;
}
DEV float b2f(u16 u) {
  __hip_bfloat16 h; __builtin_memcpy(&h, &u, 2);
  return __bfloat162float(h);
}

DEV void gload16(const void* g, void* l) {
  __builtin_amdgcn_global_load_lds((const __attribute__((address_space(1))) void*)g,
                                   (__attribute__((address_space(3))) void*)l, 16, 0, 0);
}

DEV float blk_sum256(float v, float* sbuf) {
#pragma unroll
  for (int o = 32; o; o >>= 1) v += __shfl_xor(v, o, 64);
  int w = threadIdx.x >> 6;
  if ((threadIdx.x & 63) == 0) sbuf[w] = v;
  __syncthreads();
  return sbuf[0] + sbuf[1] + sbuf[2] + sbuf[3];
}

// ---------------- one-shot setup: 6 weight transposes + emb f2b + rope + embed+bigram -----
// segments (blocks): transposes 55296 | embcopy 16384 | rope 128 | embed 2048 => 73856
__global__ __launch_bounds__(256) void prep_all(
    const float* __restrict__ Wq, const float* __restrict__ Wk, const float* __restrict__ Wv,
    const float* __restrict__ Wo, const float* __restrict__ Wfc, const float* __restrict__ Wpr,
    const float* __restrict__ emb,
    u16* __restrict__ WqkvT, u16* __restrict__ WoT, u16* __restrict__ WfcT,
    u16* __restrict__ WprT, u16* __restrict__ embB,
    float* __restrict__ rc, float* __restrict__ rs,
    const int* __restrict__ ids, const float* __restrict__ bg_embed,
    const float* __restrict__ bg_proj, const float* __restrict__ bg_scale_p,
    const float* __restrict__ mix0,
    float* __restrict__ x, float* __restrict__ x0, u16* __restrict__ xn) {
  int bid = blockIdx.x;
  int tid = threadIdx.x;
  if (bid < 55296) {
    const float* in; u16* out; int nx, K, N; size_t in_ls, out_ls; int base;
    if (bid < 6144)       { base = 0;     in = Wq;  out = WqkvT;           nx = 32; K = 1024; N = 1024; in_ls = 1048576; out_ls = 2097152; }
    else if (bid < 9216)  { base = 6144;  in = Wk;  out = WqkvT + 1048576; nx = 16; K = 1024; N = 512;  in_ls = 524288;  out_ls = 2097152; }
    else if (bid < 12288) { base = 9216;  in = Wv;  out = WqkvT + 1572864; nx = 16; K = 1024; N = 512;  in_ls = 524288;  out_ls = 2097152; }
    else if (bid < 18432) { base = 12288; in = Wo;  out = WoT;             nx = 32; K = 1024; N = 1024; in_ls = 1048576; out_ls = 1048576; }
    else if (bid < 36864) { base = 18432; in = Wfc; out = WfcT;            nx = 96; K = 1024; N = 3072; in_ls = 3145728; out_ls = 3145728; }
    else                  { base = 36864; in = Wpr; out = WprT;            nx = 32; K = 3072; N = 1024; in_ls = 3145728; out_ls = 3145728; }
    int local = bid - base;
    int kx = local % nx;
    int rest = local / nx;
    int ny = K >> 5;
    int ky = rest % ny;
    int l = rest / ny;
    __shared__ float tile[32][33];
    const float* src = in + (size_t)l * in_ls;
    u16* dst = out + (size_t)l * out_ls;
    int k0 = ky << 5, n0 = kx << 5;
    int tx = tid & 31, ty = tid >> 5;
#pragma unroll
    for (int i = 0; i < 32; i += 8)
      tile[ty + i][tx] = src[(size_t)(k0 + ty + i) * N + n0 + tx];
    __syncthreads();
#pragma unroll
    for (int i = 0; i < 32; i += 8)
      dst[(size_t)(n0 + ty + i) * K + k0 + tx] = f2b(tile[tx][ty + i]);
  } else if (bid < 71680) {
    size_t i = ((size_t)(bid - 55296) * 256 + tid) * 8;
    float4 a = *(const float4*)(emb + i);
    float4 b = *(const float4*)(emb + i + 4);
    u16x8 o;
    o[0] = f2b(a.x); o[1] = f2b(a.y); o[2] = f2b(a.z); o[3] = f2b(a.w);
    o[4] = f2b(b.x); o[5] = f2b(b.y); o[6] = f2b(b.z); o[7] = f2b(b.w);
    *(u16x8*)(embB + i) = o;
  } else if (bid < 71808) {
    int idx = (bid - 71680) * 256 + tid;
    int t = idx >> 5, i2 = idx & 31;
    float inv = expf(-((float)(2 * i2) / (float)HDIM) * logf(10000.0f));
    float ang = (float)t * inv;
    rc[idx] = cosf(ang);
    rs[idx] = sinf(ang);
  } else {
    __shared__ float be[128];
    __shared__ float sbuf[4];
    int tok = bid - 71808;
    int t = tok & (T_SEQ - 1);
    int id = ids[tok];
    int hsh = 0;
    if (t > 0) {
      int prev = ids[tok - 1];
      hsh = ((id * 36313) ^ (prev * 27191)) % 4095;
    }
    if (tid < 128) be[tid] = bg_embed[hsh * 128 + tid];
    __syncthreads();
    float scale = bg_scale_p[0];
    const float4* bp = (const float4*)bg_proj;
    float ax = 0.f, ay = 0.f, az = 0.f, aw = 0.f;
#pragma unroll 4
    for (int j = 0; j < 128; ++j) {
      float bj = be[j];
      float4 p = bp[j * 256 + tid];
      ax += bj * p.x; ay += bj * p.y; az += bj * p.z; aw += bj * p.w;
    }
    float4 e = *(const float4*)(emb + (size_t)id * DIM + tid * 4);
    float vx = e.x + ax * scale, vy = e.y + ay * scale;
    float vz = e.z + az * scale, vw = e.w + aw * scale;
    float ss = vx * vx + vy * vy + vz * vz + vw * vw;
    float tot = blk_sum256(ss, sbuf);
    float rn = rsqrtf(tot * (1.0f / DIM) + EPSF);
    float4 o; o.x = vx * rn; o.y = vy * rn; o.z = vz * rn; o.w = vw * rn;
    size_t base = (size_t)tok * DIM + tid * 4;
    *(float4*)(x0 + base) = o;
    float4 m0 = *(const float4*)(mix0 + tid * 4);
    float4 m1 = *(const float4*)(mix0 + DIM + tid * 4);
    float4 a;
    a.x = (m0.x + m1.x) * o.x;
    a.y = (m0.y + m1.y) * o.y;
    a.z = (m0.z + m1.z) * o.z;
    a.w = (m0.w + m1.w) * o.w;
    *(float4*)(x + base) = a;
    __syncthreads();
    float ss2 = a.x * a.x + a.y * a.y + a.z * a.z + a.w * a.w;
    float tot2 = blk_sum256(ss2, sbuf);
    float rn2 = rsqrtf(tot2 * (1.0f / DIM) + EPSF);
    u16x4 q;
    q[0] = f2b(a.x * rn2); q[1] = f2b(a.y * rn2); q[2] = f2b(a.z * rn2); q[3] = f2b(a.w * rn2);
    *(u16x4*)(xn + base) = q;
  }
}

// ---------------- unified residual-fold + mix + rms kernel (bf16 partials) ----------------
template <int NP, int MIX>
__global__ __launch_bounds__(256) void norm_k(float* __restrict__ x,
    const u16* __restrict__ parts, const float* __restrict__ colscale,
    const float* __restrict__ mixl, const float* __restrict__ x0,
    u16* __restrict__ xn) {
  __shared__ float sbuf[4];
  int tok = blockIdx.x, tid = threadIdx.x;
  size_t base = (size_t)tok * DIM + tid * 4;
  float4 a = *(const float4*)(x + base);
  if (NP > 0) {
    float4 cs = *(const float4*)(colscale + tid * 4);
    u16x4 p0 = *(const u16x4*)(parts + base);
    u16x4 p1 = *(const u16x4*)(parts + PSTRIDE + base);
    float sx = b2f(p0[0]) + b2f(p1[0]);
    float sy = b2f(p0[1]) + b2f(p1[1]);
    float sz = b2f(p0[2]) + b2f(p1[2]);
    float sw = b2f(p0[3]) + b2f(p1[3]);
    if (NP == 3) {
      u16x4 p2 = *(const u16x4*)(parts + 2 * PSTRIDE + base);
      sx += b2f(p2[0]); sy += b2f(p2[1]); sz += b2f(p2[2]); sw += b2f(p2[3]);
    }
    a.x += cs.x * sx; a.y += cs.y * sy; a.z += cs.z * sz; a.w += cs.w * sw;
  }
  if (MIX) {
    float4 m0 = *(const float4*)(mixl + tid * 4);
    float4 m1 = *(const float4*)(mixl + DIM + tid * 4);
    float4 b = *(const float4*)(x0 + base);
    a.x = m0.x * a.x + m1.x * b.x;
    a.y = m0.y * a.y + m1.y * b.y;
    a.z = m0.z * a.z + m1.z * b.z;
    a.w = m0.w * a.w + m1.w * b.w;
  }
  float ss = a.x * a.x + a.y * a.y + a.z * a.z + a.w * a.w;
  float tot = blk_sum256(ss, sbuf);
  float rn = rsqrtf(tot * (1.0f / DIM) + EPSF);
  if (NP > 0 || MIX) *(float4*)(x + base) = a;
  u16x4 q;
  q[0] = f2b(a.x * rn); q[1] = f2b(a.y * rn); q[2] = f2b(a.z * rn); q[3] = f2b(a.w * rn);
  *(u16x4*)(xn + base) = q;
}

// ---------------- GEMM: C(MxN) = A(MxK) @ Bt(NxK)^T, bf16 in, f32 acc ----------------
// EPI 1: partial store Cb[z][row][col] = bf16(acc) (folded later in norm_k)
// EPI 2: Cb = bf16(relu(acc)^2)
template <int EPI, int BN>
__global__ __launch_bounds__(256, (BN == 64 ? 3 : 2)) void gemm_bt(
    const u16* __restrict__ A, const u16* __restrict__ Bt,
    u16* __restrict__ Cb,
    int N, int K, int kpn) {
  constexpr int MF = (BN == 128) ? 4 : 2;
  constexpr int ASZ = 128 * 64;   // u16 per buffer
  constexpr int BSZ = BN * 64;
  constexpr int NLD = 4 + BN / 32;
  __shared__ u16 As[2 * ASZ];
  __shared__ u16 Bs[2 * BSZ];
  int tid = threadIdx.x;
  int wid = tid >> 6, lane = tid & 63;
  int g = lane >> 4, c = lane & 15;
  int row0 = blockIdx.y << 7, col0 = blockIdx.x * BN;
  int kbase = blockIdx.z * kpn;
  int wr = (BN == 128) ? ((wid >> 1) << 6) : (wid << 5);
  int wc = (BN == 128) ? ((wid & 1) << 6) : 0;
  f32x4 acc[MF][4] = {};

  int sr = lane >> 3;      // row within 8-row segment
  int kb = lane & 7;       // 16B block within row
  const u16* srcA[4];
  int ldsA[4];
#pragma unroll
  for (int i = 0; i < 4; ++i) {
    int s = (wid << 2) + i;
    int r = (s << 3) + sr;
    srcA[i] = A + (size_t)(row0 + r) * K + kbase + ((kb ^ (r & 7)) << 3);
    ldsA[i] = s << 9;
  }
  const u16* srcB[BN / 32];
  int ldsB[BN / 32];
#pragma unroll
  for (int i = 0; i < BN / 32; ++i) {
    int s = wid * (BN / 32) + i;
    int r = (s << 3) + sr;
    srcB[i] = Bt + (size_t)(col0 + r) * K + kbase + ((kb ^ (r & 7)) << 3);
    ldsB[i] = s << 9;
  }

#pragma unroll
  for (int i = 0; i < 4; ++i) gload16(srcA[i], As + ldsA[i]);
#pragma unroll
  for (int i = 0; i < BN / 32; ++i) gload16(srcB[i], Bs + ldsB[i]);

  int nk = kpn >> 6;
  for (int t = 0; t < nk; ++t) {
    int cur = t & 1;
    if (t + 1 < nk) {
      int nxt = cur ^ 1;
      int ko = (t + 1) << 6;
#pragma unroll
      for (int i = 0; i < 4; ++i) gload16(srcA[i] + ko, As + nxt * ASZ + ldsA[i]);
#pragma unroll
      for (int i = 0; i < BN / 32; ++i) gload16(srcB[i] + ko, Bs + nxt * BSZ + ldsB[i]);
      if constexpr (NLD == 6) asm volatile("s_waitcnt vmcnt(6)" ::: "memory");
      else asm volatile("s_waitcnt vmcnt(8)" ::: "memory");
    } else {
      asm volatile("s_waitcnt vmcnt(0)" ::: "memory");
    }
    __builtin_amdgcn_s_barrier();
    MEMFENCE;
    const u16* ab = As + cur * ASZ;
    const u16* bb = Bs + cur * BSZ;
#pragma unroll
    for (int ks = 0; ks < 2; ++ks) {
      bf16x8 af[MF], bfr[4];
#pragma unroll
      for (int m = 0; m < MF; ++m) {
        int r = wr + m * 16 + c;
        int kbs = ((ks << 2) + g) ^ (r & 7);
        af[m] = *(const bf16x8*)(ab + r * 64 + (kbs << 3));
      }
#pragma unroll
      for (int n = 0; n < 4; ++n) {
        int r = wc + n * 16 + c;
        int kbs = ((ks << 2) + g) ^ (r & 7);
        bfr[n] = *(const bf16x8*)(bb + r * 64 + (kbs << 3));
      }
      __builtin_amdgcn_s_setprio(1);
#pragma unroll
      for (int m = 0; m < MF; ++m)
#pragma unroll
        for (int n = 0; n < 4; ++n)
          acc[m][n] = __builtin_amdgcn_mfma_f32_16x16x32_bf16(af[m], bfr[n], acc[m][n], 0, 0, 0);
      __builtin_amdgcn_s_setprio(0);
    }
    MEMFENCE;
    __builtin_amdgcn_s_barrier();
  }

  size_t zoff = (size_t)blockIdx.z * PSTRIDE;
#pragma unroll
  for (int m = 0; m < MF; ++m) {
#pragma unroll
    for (int n = 0; n < 4; ++n) {
      int gcol = col0 + wc + n * 16 + c;
#pragma unroll
      for (int j = 0; j < 4; ++j) {
        int grow = row0 + wr + m * 16 + g * 4 + j;
        float v = acc[m][n][j];
        if (EPI == 1) {
          Cb[zoff + (size_t)grow * N + gcol] = f2b(v);
        } else if (EPI == 2) {
          float r = v > 0.f ? v : 0.f;
          Cb[(size_t)grow * N + gcol] = f2b(r * r);
        }
      }
    }
  }
}

// ---------------- LM-head GEMM: 256x256 tile, BK=64, 8-phase interleaved schedule ---------
// m201-style port (r18-proven 209us). This round: stage issued BEFORE ds_read frags within
// each phase (stage target always disjoint from phase's read regions; semantics unchanged).
// Calendar: P0:A-h0(t1) P1:A-h1(t1) P2:B-h0(t0+2) P3:B-h1(t0+2) P4:A-h0(t0+2) P5:A-h1(t0+2)
// P6:B-h0(t1+2) P7:B-h1(t1+2); vmcnt(4) at P0/P4 (minimal), vmcnt(0) at last iter's P4.
__global__ __launch_bounds__(512, 2) void gemm_lmhead(
    const u16* __restrict__ A, const u16* __restrict__ Bt,
    const int* __restrict__ tgt, float* __restrict__ pM, float* __restrict__ pS,
    float* __restrict__ loTgt) {
  constexpr int K = 1024;
  constexpr int TSZ = 256 * 64;           // u16 per tile buffer (32 KB)
  __shared__ u16 As[2 * TSZ];
  __shared__ u16 Bs[2 * TSZ];
  int tid = threadIdx.x;
  int wid = tid >> 6, lane = tid & 63;
  int wm = wid >> 2, wn = wid & 3;
  int g = lane >> 4, c = lane & 15;
  int bid = blockIdx.x;
  int swz = ((bid & 7) << 7) + (bid >> 3);
  int colb = swz >> 3, rowb = swz & 7;
  int row0 = rowb << 8, col0 = colb << 8;
  f32x4 acc[8][4] = {};

  int sr = lane >> 3, kb = lane & 7;
  const u16* srcA[2][2];
  const u16* srcB[2][2];
  int ldsOff[2][2];
#pragma unroll
  for (int h = 0; h < 2; ++h)
#pragma unroll
    for (int i = 0; i < 2; ++i) {
      int s = (h << 4) + (wid << 1) + i;
      int r = (s << 3) + sr;
      srcA[h][i] = A + (size_t)(row0 + r) * K + ((kb ^ (r & 7)) << 3);
      srcB[h][i] = Bt + (size_t)(col0 + r) * K + ((kb ^ (r & 7)) << 3);
      ldsOff[h][i] = s << 9;
    }

  auto stageA = [&](int T, int h) {
    int ko = T << 6;
    int bo = (T & 1) * TSZ;
#pragma unroll
    for (int i = 0; i < 2; ++i) gload16(srcA[h][i] + ko, As + bo + ldsOff[h][i]);
  };
  auto stageB = [&](int T, int h) {
    int ko = T << 6;
    int bo = (T & 1) * TSZ;
#pragma unroll
    for (int i = 0; i < 2; ++i) gload16(srcB[h][i] + ko, Bs + bo + ldsOff[h][i]);
  };

  // prologue: B(0), A(0), B(1) — 12 loads/thread; P0's vmcnt(4) waits through A(0)
  stageB(0, 0); stageB(0, 1);
  stageA(0, 0); stageA(0, 1);
  stageB(1, 0); stageB(1, 1);

  bf16x8 bfr[4][2];
  for (int kt2 = 0; kt2 < 16; kt2 += 2) {
#pragma unroll
    for (int p = 0; p < 8; ++p) {
      int tt = p >> 2;           // tile within pair (== LDS buffer, kt2 even)
      int q = p & 3;             // output quadrant (m-frags 2q, 2q+1)
      int bo = tt * TSZ;
      if (p == 0) {
        asm volatile("s_waitcnt vmcnt(4)" ::: "memory");
      } else if (p == 4) {
        if (kt2 == 14) { asm volatile("s_waitcnt vmcnt(0)" ::: "memory"); }
        else           { asm volatile("s_waitcnt vmcnt(4)" ::: "memory"); }
      }
      __builtin_amdgcn_s_barrier();
      MEMFENCE;
      // stage FIRST (target regions disjoint from this phase's reads), then ds_reads
      if (p == 0)      { stageA(kt2 + 1, 0); }
      else if (p == 1) { stageA(kt2 + 1, 1); }
      else if (p == 2) { if (kt2 + 2 < 16) stageB(kt2 + 2, 0); }
      else if (p == 3) { if (kt2 + 2 < 16) stageB(kt2 + 2, 1); }
      else if (p == 4) { if (kt2 + 2 < 16) stageA(kt2 + 2, 0); }
      else if (p == 5) { if (kt2 + 2 < 16) stageA(kt2 + 2, 1); }
      else if (p == 6) { if (kt2 + 3 < 16) stageB(kt2 + 3, 0); }
      else             { if (kt2 + 3 < 16) stageB(kt2 + 3, 1); }
      if (q == 0) {
#pragma unroll
        for (int nf = 0; nf < 4; ++nf) {
          int r = (wn << 6) + nf * 16 + c;
#pragma unroll
          for (int ks = 0; ks < 2; ++ks) {
            int kbs = ((ks << 2) + g) ^ (r & 7);
            bfr[nf][ks] = *(const bf16x8*)(Bs + bo + r * 64 + (kbs << 3));
          }
        }
      }
      bf16x8 af[2][2];
#pragma unroll
      for (int mi = 0; mi < 2; ++mi) {
        int r = (wm << 7) + ((q << 1) + mi) * 16 + c;
#pragma unroll
        for (int ks = 0; ks < 2; ++ks) {
          int kbs = ((ks << 2) + g) ^ (r & 7);
          af[mi][ks] = *(const bf16x8*)(As + bo + r * 64 + (kbs << 3));
        }
      }
      MEMFENCE;
      __builtin_amdgcn_s_barrier();
      __builtin_amdgcn_s_setprio(1);
#pragma unroll
      for (int ks = 0; ks < 2; ++ks)
#pragma unroll
        for (int mi = 0; mi < 2; ++mi)
#pragma unroll
          for (int nf = 0; nf < 4; ++nf)
            acc[(q << 1) + mi][nf] = __builtin_amdgcn_mfma_f32_16x16x32_bf16(
                af[mi][ks], bfr[nf][ks], acc[(q << 1) + mi][nf], 0, 0, 0);
      __builtin_amdgcn_s_setprio(0);
    }
  }

  int cb = (col0 >> 6) + wn;
#pragma unroll
  for (int mf = 0; mf < 8; ++mf) {
#pragma unroll
    for (int j = 0; j < 4; ++j) {
      int grow = row0 + (wm << 7) + mf * 16 + g * 4 + j;
      int tg = tgt[grow];
      float sv[4];
      float mx = -3.0e38f;
#pragma unroll
      for (int nf = 0; nf < 4; ++nf) {
        float a = acc[mf][nf][j] * (1.0f / SCAP);
        a = fminf(fmaxf(a, -15.f), 15.f);
        float e = __expf(2.0f * a);
        float tt = SCAP * (e - 1.0f) / (e + 1.0f);
        sv[nf] = tt;
        mx = fmaxf(mx, tt);
        int gcol = col0 + (wn << 6) + nf * 16 + c;
        if (gcol == tg) loTgt[grow] = tt;
      }
      mx = fmaxf(mx, __shfl_xor(mx, 1, 64));
      mx = fmaxf(mx, __shfl_xor(mx, 2, 64));
      mx = fmaxf(mx, __shfl_xor(mx, 4, 64));
      mx = fmaxf(mx, __shfl_xor(mx, 8, 64));
      float s = 0.f;
#pragma unroll
      for (int nf = 0; nf < 4; ++nf) s += __expf(sv[nf] - mx);
      s += __shfl_xor(s, 1, 64);
      s += __shfl_xor(s, 2, 64);
      s += __shfl_xor(s, 4, 64);
      s += __shfl_xor(s, 8, 64);
      if (c == 0) {
        pM[(size_t)grow * NCB + cb] = mx;
        pS[(size_t)grow * NCB + cb] = s;
      }
    }
  }
}

// ---------------- fused QKV GEMM: epilogue does q/k rms+rope+qg and v(+ve)->vT ----------------
__global__ __launch_bounds__(256, 3) void gemm_qkv(
    const u16* __restrict__ A, const u16* __restrict__ Bt,
    const float* __restrict__ qg_l, const float* __restrict__ rc, const float* __restrict__ rs,
    const float* __restrict__ ve, const int* __restrict__ ids, int vb,
    u16* __restrict__ qB, u16* __restrict__ kB, u16* __restrict__ vT) {
  constexpr int K = 1024;
  constexpr int ASZ = 128 * 64;
  constexpr int BSZ = 64 * 64;
  __shared__ u16 As[2 * ASZ];
  __shared__ u16 Bs[2 * BSZ];
  int tid = threadIdx.x;
  int wid = tid >> 6, lane = tid & 63;
  int g = lane >> 4, c = lane & 15;
  int bx = blockIdx.x;
  int row0 = blockIdx.y << 7, col0 = bx << 6;
  f32x4 acc[2][4] = {};

  int sr = lane >> 3, kb = lane & 7;
  const u16* srcA[4];
  int ldsA[4];
#pragma unroll
  for (int i = 0; i < 4; ++i) {
    int s = (wid << 2) + i;
    int r = (s << 3) + sr;
    srcA[i] = A + (size_t)(row0 + r) * K + ((kb ^ (r & 7)) << 3);
    ldsA[i] = s << 9;
  }
  const u16* srcB[2];
  int ldsB[2];
#pragma unroll
  for (int i = 0; i < 2; ++i) {
    int s = (wid << 1) + i;
    int r = (s << 3) + sr;
    srcB[i] = Bt + (size_t)(col0 + r) * K + ((kb ^ (r & 7)) << 3);
    ldsB[i] = s << 9;
  }

#pragma unroll
  for (int i = 0; i < 4; ++i) gload16(srcA[i], As + ldsA[i]);
#pragma unroll
  for (int i = 0; i < 2; ++i) gload16(srcB[i], Bs + ldsB[i]);

  for (int t = 0; t < 16; ++t) {
    int cur = t & 1;
    if (t + 1 < 16) {
      int nxt = cur ^ 1;
      int ko = (t + 1) << 6;
#pragma unroll
      for (int i = 0; i < 4; ++i) gload16(srcA[i] + ko, As + nxt * ASZ + ldsA[i]);
#pragma unroll
      for (int i = 0; i < 2; ++i) gload16(srcB[i] + ko, Bs + nxt * BSZ + ldsB[i]);
      asm volatile("s_waitcnt vmcnt(6)" ::: "memory");
    } else {
      asm volatile("s_waitcnt vmcnt(0)" ::: "memory");
    }
    __builtin_amdgcn_s_barrier();
    MEMFENCE;
    const u16* ab = As + cur * ASZ;
    const u16* bb = Bs + cur * BSZ;
#pragma unroll
    for (int ks = 0; ks < 2; ++ks) {
      bf16x8 af[2], bfr[4];
#pragma unroll
      for (int m = 0; m < 2; ++m) {
        int r = (wid << 5) + m * 16 + c;
        int kbs = ((ks << 2) + g) ^ (r & 7);
        af[m] = *(const bf16x8*)(ab + r * 64 + (kbs << 3));
      }
#pragma unroll
      for (int n = 0; n < 4; ++n) {
        int r = n * 16 + c;
        int kbs = ((ks << 2) + g) ^ (r & 7);
        bfr[n] = *(const bf16x8*)(bb + r * 64 + (kbs << 3));
      }
      __builtin_amdgcn_s_setprio(1);
#pragma unroll
      for (int m = 0; m < 2; ++m)
#pragma unroll
        for (int n = 0; n < 4; ++n)
          acc[m][n] = __builtin_amdgcn_mfma_f32_16x16x32_bf16(af[m], bfr[n], acc[m][n], 0, 0, 0);
      __builtin_amdgcn_s_setprio(0);
    }
    MEMFENCE;
    __builtin_amdgcn_s_barrier();
  }

  int b = row0 >> 10;
  if (bx < 24) {
    bool isq = (bx < 16);
    int h = isq ? bx : bx - 16;
    float gmul = isq ? qg_l[h] * 0.125f : 1.0f;
    u16* hb = isq ? (qB + ((size_t)(b * NHD + h)) * T_SEQ * HDIM)
                  : (kB + ((size_t)(b * NKVH + h)) * T_SEQ * HDIM);
#pragma unroll
    for (int m = 0; m < 2; ++m) {
#pragma unroll
      for (int j = 0; j < 4; ++j) {
        int grow = row0 + (wid << 5) + m * 16 + g * 4 + j;
        int t = grow & (T_SEQ - 1);
        float vv[4];
        float ss = 0.f;
#pragma unroll
        for (int n = 0; n < 4; ++n) { vv[n] = acc[m][n][j]; ss += vv[n] * vv[n]; }
        ss += __shfl_xor(ss, 1, 64);
        ss += __shfl_xor(ss, 2, 64);
        ss += __shfl_xor(ss, 4, 64);
        ss += __shfl_xor(ss, 8, 64);
        float rn = rsqrtf(ss * (1.0f / HDIM) + EPSF);
#pragma unroll
        for (int n = 0; n < 4; ++n) vv[n] *= rn;
        float c0 = rc[t * 32 + c], s0 = rs[t * 32 + c];
        float c1 = rc[t * 32 + 16 + c], s1 = rs[t * 32 + 16 + c];
        float o0 = vv[0] * c0 + vv[2] * s0;
        float o1 = vv[1] * c1 + vv[3] * s1;
        float o2 = vv[2] * c0 - vv[0] * s0;
        float o3 = vv[3] * c1 - vv[1] * s1;
        u16* dst = hb + (size_t)t * HDIM;
        dst[c] = f2b(o0 * gmul);
        dst[16 + c] = f2b(o1 * gmul);
        dst[32 + c] = f2b(o2 * gmul);
        dst[48 + c] = f2b(o3 * gmul);
      }
    }
  } else {
    int kh = bx - 24;
#pragma unroll
    for (int m = 0; m < 2; ++m) {
#pragma unroll
      for (int j = 0; j < 4; ++j) {
        int grow = row0 + (wid << 5) + m * 16 + g * 4 + j;
        int lr = (wid << 5) + m * 16 + g * 4 + j;
        int id = ids[grow];
        const float* vl = ve + ((size_t)vb * VOC + id) * KVD + kh * HDIM;
#pragma unroll
        for (int n = 0; n < 4; ++n)
          As[lr * 72 + n * 16 + c] = f2b(acc[m][n][j] + vl[n * 16 + c]);
      }
    }
    __syncthreads();
    int hd = tid & 63, seg = tid >> 6;
    int t0 = (row0 & (T_SEQ - 1)) + seg * 32;
    u16* dst = vT + (((size_t)(b * NKVH + kh)) * HDIM + hd) * T_SEQ + t0;
#pragma unroll
    for (int i = 0; i < 32; i += 8) {
      u16x8 o;
#pragma unroll
      for (int e = 0; e < 8; ++e) o[e] = As[(seg * 32 + i + e) * 72 + hd];
      *(u16x8*)(dst + i) = o;
    }
  }
}

// ---------------- flash attention: static-max softmax, ones rowsum, 2-deep KV prefetch ----
// (r15-proven: grid (16, NHD, B), block 128, 32-row strips paired (s, 31-s).)
__global__ __launch_bounds__(128) void attn_kernel(const u16* __restrict__ qB,
    const u16* __restrict__ kB, const u16* __restrict__ vT, const float* __restrict__ qg_l,
    u16* __restrict__ attout) {
  __shared__ u16 plds[2][32 * 76];
  int b = blockIdx.z, h = blockIdx.y;
  int kh = h >> 1;
  int wid = threadIdx.x >> 6, lane = threadIdx.x & 63;
  int g = lane >> 4, c = lane & 15;
  int strip = wid ? (31 - (int)blockIdx.x) : (int)blockIdx.x;
  int qr0 = strip << 5;
  const u16* qptr = qB + ((size_t)(b * NHD + h)) * T_SEQ * HDIM;
  const u16* kptr = kB + ((size_t)(b * NKVH + kh)) * T_SEQ * HDIM;
  const u16* vptr = vT + ((size_t)(b * NKVH + kh)) * HDIM * T_SEQ;
  u16* pw = plds[wid];
  float Mh = fabsf(qg_l[h]) * 8.0f;

  bf16x8 aq[2][2];
#pragma unroll
  for (int m = 0; m < 2; ++m)
#pragma unroll
    for (int ks = 0; ks < 2; ++ks)
      aq[m][ks] = *(const bf16x8*)(qptr + (qr0 + m * 16 + c) * HDIM + ks * 32 + g * 8);

  bf16x8 vone;
#pragma unroll
  for (int e = 0; e < 8; ++e) vone[e] = (short)0x3F80;

  f32x4 oacc[2][4] = {};
  f32x4 lacc[2] = {};

  bf16x8 kR0[4][2], vR0[4][2], kR1[4][2], vR1[4][2];

  auto LOADKV = [&](bf16x8 (&bk)[4][2], bf16x8 (&bv)[4][2], int kv0) {
#pragma unroll
    for (int n = 0; n < 4; ++n)
#pragma unroll
      for (int ks = 0; ks < 2; ++ks) {
        bk[n][ks] = *(const bf16x8*)(kptr + (kv0 + n * 16 + c) * HDIM + ks * 32 + g * 8);
        bv[n][ks] = *(const bf16x8*)(vptr + (n * 16 + c) * T_SEQ + kv0 + ks * 32 + g * 8);
      }
  };

  auto BODY = [&](bf16x8 (&bk)[4][2], bf16x8 (&bv)[4][2], int kv0) {
    f32x4 sc[2][4] = {};
#pragma unroll
    for (int ks = 0; ks < 2; ++ks)
#pragma unroll
      for (int m = 0; m < 2; ++m)
#pragma unroll
        for (int n = 0; n < 4; ++n)
          sc[m][n] = __builtin_amdgcn_mfma_f32_16x16x32_bf16(aq[m][ks], bk[n][ks], sc[m][n], 0, 0, 0);
    bool maskT = (kv0 + 64 > qr0);
#pragma unroll
    for (int m = 0; m < 2; ++m) {
#pragma unroll
      for (int j = 0; j < 4; ++j) {
        int row = qr0 + m * 16 + g * 4 + j;
        float p0 = __expf(sc[m][0][j] - Mh);
        float p1 = __expf(sc[m][1][j] - Mh);
        float p2 = __expf(sc[m][2][j] - Mh);
        float p3 = __expf(sc[m][3][j] - Mh);
        if (maskT) {
          if (kv0 + c > row) p0 = 0.f;
          if (kv0 + 16 + c > row) p1 = 0.f;
          if (kv0 + 32 + c > row) p2 = 0.f;
          if (kv0 + 48 + c > row) p3 = 0.f;
        }
        int pr = m * 16 + g * 4 + j;
        pw[pr * 76 + c] = f2b(p0);
        pw[pr * 76 + 16 + c] = f2b(p1);
        pw[pr * 76 + 32 + c] = f2b(p2);
        pw[pr * 76 + 48 + c] = f2b(p3);
      }
    }
    MEMFENCE;
    bf16x8 ap[2][2];
#pragma unroll
    for (int m = 0; m < 2; ++m)
#pragma unroll
      for (int ks = 0; ks < 2; ++ks) {
        u16x8 tmp = *(const u16x8*)(pw + (m * 16 + c) * 76 + ks * 32 + g * 8);
        __builtin_memcpy(&ap[m][ks], &tmp, 16);
      }
#pragma unroll
    for (int ks = 0; ks < 2; ++ks) {
#pragma unroll
      for (int m = 0; m < 2; ++m) {
#pragma unroll
        for (int n = 0; n < 4; ++n)
          oacc[m][n] = __builtin_amdgcn_mfma_f32_16x16x32_bf16(ap[m][ks], bv[n][ks], oacc[m][n], 0, 0, 0);
        lacc[m] = __builtin_amdgcn_mfma_f32_16x16x32_bf16(ap[m][ks], vone, lacc[m], 0, 0, 0);
      }
    }
  };

  LOADKV(kR0, vR0, 0);
  int kv0 = 0;
  while (true) {
    if (kv0 + 64 <= qr0) LOADKV(kR1, vR1, kv0 + 64);
    BODY(kR0, vR0, kv0);
    kv0 += 64;
    if (kv0 > qr0) break;
    if (kv0 + 64 <= qr0) LOADKV(kR0, vR0, kv0 + 64);
    BODY(kR1, vR1, kv0);
    kv0 += 64;
    if (kv0 > qr0) break;
  }

#pragma unroll
  for (int m = 0; m < 2; ++m) {
#pragma unroll
    for (int j = 0; j < 4; ++j) {
      float inv = 1.0f / lacc[m][j];
      int trow = qr0 + m * 16 + g * 4 + j;
      u16* orow = attout + ((size_t)(b * T_SEQ + trow)) * DIM + h * HDIM;
#pragma unroll
      for (int n = 0; n < 4; ++n)
        orow[n * 16 + c] = f2b(oacc[m][n][j] * inv);
    }
  }
}

// ---------------- LM-head merge: combine 512 per-colblock partials -> nll per token ----------
__global__ __launch_bounds__(256) void lse_merge(const float* __restrict__ pM,
    const float* __restrict__ pS, const float* __restrict__ loTgt, float* __restrict__ nll) {
  __shared__ float sbuf[4];
  int tok = blockIdx.x, tid = threadIdx.x;
  int wid = tid >> 6, lane = tid & 63;
  const float* rm = pM + (size_t)tok * NCB;
  const float* rs = pS + (size_t)tok * NCB;
  float m0 = rm[tid], m1 = rm[tid + 256];
  float mx = fmaxf(m0, m1);
#pragma unroll
  for (int o = 32; o; o >>= 1) mx = fmaxf(mx, __shfl_xor(mx, o, 64));
  if (lane == 0) sbuf[wid] = mx;
  __syncthreads();
  float M = fmaxf(fmaxf(sbuf[0], sbuf[1]), fmaxf(sbuf[2], sbuf[3]));
  __syncthreads();
  float s = rs[tid] * __expf(m0 - M) + rs[tid + 256] * __expf(m1 - M);
  float S = blk_sum256(s, sbuf);
  if (tid == 0) nll[tok] = logf(S) + M - loTgt[tok];
}

__global__ __launch_bounds__(256) void loss_final(const float* __restrict__ nll,
    float* __restrict__ out) {
  __shared__ float sbuf[4];
  int tid = threadIdx.x;
  float acc = 0.f;
  for (int i = tid; i < NTOK; i += 256) acc += nll[i];
  float tot = blk_sum256(acc, sbuf);
  if (tid == 0) out[0] = tot * (1.0f / NTOK);
}

// ---------------- host ----------------
extern "C" void kernel_launch(void* const* d_in, const int* in_sizes, int n_in,
                              void* d_out, int out_size, void* d_ws, size_t ws_size,
                              hipStream_t stream) {
  (void)in_sizes; (void)n_in; (void)out_size; (void)ws_size;
  const int* ids = (const int*)d_in[0];
  const int* tgt = (const int*)d_in[1];
  const float* emb = (const float*)d_in[2];
  const float* bg_embed = (const float*)d_in[3];
  const float* bg_proj = (const float*)d_in[4];
  const float* bg_scale = (const float*)d_in[5];
  const float* ve = (const float*)d_in[6];
  const float* Wq = (const float*)d_in[7];
  const float* Wk = (const float*)d_in[8];
  const float* Wv = (const float*)d_in[9];
  const float* Wo = (const float*)d_in[10];
  const float* qg = (const float*)d_in[11];
  const float* a_s = (const float*)d_in[12];
  const float* m_s = (const float*)d_in[13];
  const float* mix = (const float*)d_in[14];
  const float* Wfc = (const float*)d_in[15];
  const float* Wpr = (const float*)d_in[16];

  char* w = (char*)d_ws;
  auto alloc = [&](size_t bytes) {
    char* p = w;
    w += (bytes + 255) & ~(size_t)255;
    return p;
  };
  u16* WqkvT = (u16*)alloc(6ull * 2048 * 1024 * 2);
  u16* WoT   = (u16*)alloc(6ull * 1024 * 1024 * 2);
  u16* WfcT  = (u16*)alloc(6ull * 3072 * 1024 * 2);
  u16* WprT  = (u16*)alloc(6ull * 1024 * 3072 * 2);
  u16* embB  = (u16*)alloc((size_t)VOC * DIM * 2);
  float* x   = (float*)alloc((size_t)NTOK * DIM * 4);
  float* x0  = (float*)alloc((size_t)NTOK * DIM * 4);
  u16* xn    = (u16*)alloc((size_t)NTOK * DIM * 2);
  u16* qBuf  = (u16*)alloc((size_t)NTOK * DIM * 2);
  u16* kBuf  = (u16*)alloc((size_t)NTOK * KVD * 2);
  u16* vTb   = (u16*)alloc((size_t)NTOK * KVD * 2);
  u16* attout = (u16*)alloc((size_t)NTOK * DIM * 2);
  u16* xmlp  = (u16*)alloc((size_t)NTOK * DIM * 2);
  u16* hmid  = (u16*)alloc((size_t)NTOK * MLPD * 2);
  u16* pparts = (u16*)alloc(3 * PSTRIDE * 2);
  float* rc  = (float*)alloc((size_t)T_SEQ * 32 * 4);
  float* rs  = (float*)alloc((size_t)T_SEQ * 32 * 4);
  float* pM  = (float*)alloc((size_t)NTOK * NCB * 4);
  float* pS  = (float*)alloc((size_t)NTOK * NCB * 4);
  float* loTgt = (float*)alloc(NTOK * 4);
  float* nll = (float*)alloc(NTOK * 4);

  prep_all<<<73856, 256, 0, stream>>>(Wq, Wk, Wv, Wo, Wfc, Wpr, emb,
      WqkvT, WoT, WfcT, WprT, embB, rc, rs,
      ids, bg_embed, bg_proj, bg_scale, mix, x, x0, xn);

  int lprev = 0;
  for (int step = 0; step < 12; ++step) {
    int l = step % 6;
    if (step > 0)
      norm_k<3, 1><<<NTOK, 256, 0, stream>>>(x, pparts, m_s + lprev * DIM, mix + l * 2048, x0, xn);
    gemm_qkv<<<dim3(32, 16), 256, 0, stream>>>(xn, WqkvT + (size_t)l * 2048 * 1024,
        qg + l * 16, rc, rs, ve, ids, step % 5, qBuf, kBuf, vTb);
    attn_kernel<<<dim3(16, 16, 2), 128, 0, stream>>>(qBuf, kBuf, vTb, qg + l * 16, attout);
    gemm_bt<1, 64><<<dim3(16, 16, 2), 256, 0, stream>>>(attout, WoT + (size_t)l * 1024 * 1024,
        pparts, 1024, 1024, 512);
    norm_k<2, 0><<<NTOK, 256, 0, stream>>>(x, pparts, a_s + l * DIM, nullptr, nullptr, xmlp);
    gemm_bt<2, 64><<<dim3(48, 16, 1), 256, 0, stream>>>(xmlp, WfcT + (size_t)l * 3072 * 1024,
        hmid, 3072, 1024, 1024);
    gemm_bt<1, 64><<<dim3(16, 16, 3), 256, 0, stream>>>(hmid, WprT + (size_t)l * 1024 * 3072,
        pparts, 1024, 3072, 1024);
    lprev = l;
  }

  norm_k<3, 0><<<NTOK, 256, 0, stream>>>(x, pparts, m_s + lprev * DIM, nullptr, nullptr, xn);
  gemm_lmhead<<<1024, 512, 0, stream>>>(xn, embB, tgt, pM, pS, loTgt);
  lse_merge<<<NTOK, 256, 0, stream>>>(pM, pS, loTgt, nll);
  loss_final<<<1, 256, 0, stream>>>(nll, (float*)d_out);
}

// Round 20
// 1742.358 us; speedup vs baseline: 1.0071x; 1.0071x over previous
//
#include <hip/hip_runtime.h>
#include <hip/hip_bf16.h>
#include <math.h>

#define DEV __device__ __forceinline__

typedef unsigned short u16;
typedef short bf16x8 __attribute__((ext_vector_type(8)));
typedef float f32x4 __attribute__((ext_vector_type(4)));
typedef u16 u16x8 __attribute__((ext_vector_type(8)));
typedef u16 u16x4 __attribute__((ext_vector_type(4)));

#define T_SEQ 1024
#define NTOK 2048
#define DIM 1024
#define NHD 16
#define NKVH 8
#define HDIM 64
#define KVD 512
#define MLPD 3072
#define VOC 32768
#define EPSF 1.1920929e-07f
#define SCAP 30.0f
#define NCB 512   // 32768 / 64 col-blocks for LM-head partial LSE
#define PSTRIDE ((size_t)NTOK * DIM)

#define MEMFENCE asm volatile("" ::: "memory")

DEV u16 f2b(float f) {
  __hip_bfloat16 h = __float2bfloat16(f);
  u16 r; __builtin_memcpy(&r, &h, 2); return r;
}
DEV float b2f(u16 u) {
  __hip_bfloat16 h; __builtin_memcpy(&h, &u, 2);
  return __bfloat162float(h);
}

DEV void gload16(const void* g, void* l) {
  __builtin_amdgcn_global_load_lds((const __attribute__((address_space(1))) void*)g,
                                   (__attribute__((address_space(3))) void*)l, 16, 0, 0);
}

DEV float blk_sum256(float v, float* sbuf) {
#pragma unroll
  for (int o = 32; o; o >>= 1) v += __shfl_xor(v, o, 64);
  int w = threadIdx.x >> 6;
  if ((threadIdx.x & 63) == 0) sbuf[w] = v;
  __syncthreads();
  return sbuf[0] + sbuf[1] + sbuf[2] + sbuf[3];
}

// ---------------- one-shot setup: 6 weight transposes + emb f2b + rope + embed+bigram -----
// segments (blocks): transposes 55296 | embcopy 16384 | rope 128 | embed 2048 => 73856
__global__ __launch_bounds__(256) void prep_all(
    const float* __restrict__ Wq, const float* __restrict__ Wk, const float* __restrict__ Wv,
    const float* __restrict__ Wo, const float* __restrict__ Wfc, const float* __restrict__ Wpr,
    const float* __restrict__ emb,
    u16* __restrict__ WqkvT, u16* __restrict__ WoT, u16* __restrict__ WfcT,
    u16* __restrict__ WprT, u16* __restrict__ embB,
    float* __restrict__ rc, float* __restrict__ rs,
    const int* __restrict__ ids, const float* __restrict__ bg_embed,
    const float* __restrict__ bg_proj, const float* __restrict__ bg_scale_p,
    const float* __restrict__ mix0,
    float* __restrict__ x, float* __restrict__ x0, u16* __restrict__ xn) {
  int bid = blockIdx.x;
  int tid = threadIdx.x;
  if (bid < 55296) {
    const float* in; u16* out; int nx, K, N; size_t in_ls, out_ls; int base;
    if (bid < 6144)       { base = 0;     in = Wq;  out = WqkvT;           nx = 32; K = 1024; N = 1024; in_ls = 1048576; out_ls = 2097152; }
    else if (bid < 9216)  { base = 6144;  in = Wk;  out = WqkvT + 1048576; nx = 16; K = 1024; N = 512;  in_ls = 524288;  out_ls = 2097152; }
    else if (bid < 12288) { base = 9216;  in = Wv;  out = WqkvT + 1572864; nx = 16; K = 1024; N = 512;  in_ls = 524288;  out_ls = 2097152; }
    else if (bid < 18432) { base = 12288; in = Wo;  out = WoT;             nx = 32; K = 1024; N = 1024; in_ls = 1048576; out_ls = 1048576; }
    else if (bid < 36864) { base = 18432; in = Wfc; out = WfcT;            nx = 96; K = 1024; N = 3072; in_ls = 3145728; out_ls = 3145728; }
    else                  { base = 36864; in = Wpr; out = WprT;            nx = 32; K = 3072; N = 1024; in_ls = 3145728; out_ls = 3145728; }
    int local = bid - base;
    int kx = local % nx;
    int rest = local / nx;
    int ny = K >> 5;
    int ky = rest % ny;
    int l = rest / ny;
    __shared__ float tile[32][33];
    const float* src = in + (size_t)l * in_ls;
    u16* dst = out + (size_t)l * out_ls;
    int k0 = ky << 5, n0 = kx << 5;
    int tx = tid & 31, ty = tid >> 5;
#pragma unroll
    for (int i = 0; i < 32; i += 8)
      tile[ty + i][tx] = src[(size_t)(k0 + ty + i) * N + n0 + tx];
    __syncthreads();
#pragma unroll
    for (int i = 0; i < 32; i += 8)
      dst[(size_t)(n0 + ty + i) * K + k0 + tx] = f2b(tile[tx][ty + i]);
  } else if (bid < 71680) {
    size_t i = ((size_t)(bid - 55296) * 256 + tid) * 8;
    float4 a = *(const float4*)(emb + i);
    float4 b = *(const float4*)(emb + i + 4);
    u16x8 o;
    o[0] = f2b(a.x); o[1] = f2b(a.y); o[2] = f2b(a.z); o[3] = f2b(a.w);
    o[4] = f2b(b.x); o[5] = f2b(b.y); o[6] = f2b(b.z); o[7] = f2b(b.w);
    *(u16x8*)(embB + i) = o;
  } else if (bid < 71808) {
    int idx = (bid - 71680) * 256 + tid;
    int t = idx >> 5, i2 = idx & 31;
    float inv = expf(-((float)(2 * i2) / (float)HDIM) * logf(10000.0f));
    float ang = (float)t * inv;
    rc[idx] = cosf(ang);
    rs[idx] = sinf(ang);
  } else {
    __shared__ float be[128];
    __shared__ float sbuf[4];
    int tok = bid - 71808;
    int t = tok & (T_SEQ - 1);
    int id = ids[tok];
    int hsh = 0;
    if (t > 0) {
      int prev = ids[tok - 1];
      hsh = ((id * 36313) ^ (prev * 27191)) % 4095;
    }
    if (tid < 128) be[tid] = bg_embed[hsh * 128 + tid];
    __syncthreads();
    float scale = bg_scale_p[0];
    const float4* bp = (const float4*)bg_proj;
    float ax = 0.f, ay = 0.f, az = 0.f, aw = 0.f;
#pragma unroll 4
    for (int j = 0; j < 128; ++j) {
      float bj = be[j];
      float4 p = bp[j * 256 + tid];
      ax += bj * p.x; ay += bj * p.y; az += bj * p.z; aw += bj * p.w;
    }
    float4 e = *(const float4*)(emb + (size_t)id * DIM + tid * 4);
    float vx = e.x + ax * scale, vy = e.y + ay * scale;
    float vz = e.z + az * scale, vw = e.w + aw * scale;
    float ss = vx * vx + vy * vy + vz * vz + vw * vw;
    float tot = blk_sum256(ss, sbuf);
    float rn = rsqrtf(tot * (1.0f / DIM) + EPSF);
    float4 o; o.x = vx * rn; o.y = vy * rn; o.z = vz * rn; o.w = vw * rn;
    size_t base = (size_t)tok * DIM + tid * 4;
    *(float4*)(x0 + base) = o;
    float4 m0 = *(const float4*)(mix0 + tid * 4);
    float4 m1 = *(const float4*)(mix0 + DIM + tid * 4);
    float4 a;
    a.x = (m0.x + m1.x) * o.x;
    a.y = (m0.y + m1.y) * o.y;
    a.z = (m0.z + m1.z) * o.z;
    a.w = (m0.w + m1.w) * o.w;
    *(float4*)(x + base) = a;
    __syncthreads();
    float ss2 = a.x * a.x + a.y * a.y + a.z * a.z + a.w * a.w;
    float tot2 = blk_sum256(ss2, sbuf);
    float rn2 = rsqrtf(tot2 * (1.0f / DIM) + EPSF);
    u16x4 q;
    q[0] = f2b(a.x * rn2); q[1] = f2b(a.y * rn2); q[2] = f2b(a.z * rn2); q[3] = f2b(a.w * rn2);
    *(u16x4*)(xn + base) = q;
  }
}

// ---------------- unified residual-fold + mix + rms kernel (bf16 partials) ----------------
template <int NP, int MIX>
__global__ __launch_bounds__(256) void norm_k(float* __restrict__ x,
    const u16* __restrict__ parts, const float* __restrict__ colscale,
    const float* __restrict__ mixl, const float* __restrict__ x0,
    u16* __restrict__ xn) {
  __shared__ float sbuf[4];
  int tok = blockIdx.x, tid = threadIdx.x;
  size_t base = (size_t)tok * DIM + tid * 4;
  float4 a = *(const float4*)(x + base);
  if (NP > 0) {
    float4 cs = *(const float4*)(colscale + tid * 4);
    u16x4 p0 = *(const u16x4*)(parts + base);
    u16x4 p1 = *(const u16x4*)(parts + PSTRIDE + base);
    float sx = b2f(p0[0]) + b2f(p1[0]);
    float sy = b2f(p0[1]) + b2f(p1[1]);
    float sz = b2f(p0[2]) + b2f(p1[2]);
    float sw = b2f(p0[3]) + b2f(p1[3]);
    if (NP == 3) {
      u16x4 p2 = *(const u16x4*)(parts + 2 * PSTRIDE + base);
      sx += b2f(p2[0]); sy += b2f(p2[1]); sz += b2f(p2[2]); sw += b2f(p2[3]);
    }
    a.x += cs.x * sx; a.y += cs.y * sy; a.z += cs.z * sz; a.w += cs.w * sw;
  }
  if (MIX) {
    float4 m0 = *(const float4*)(mixl + tid * 4);
    float4 m1 = *(const float4*)(mixl + DIM + tid * 4);
    float4 b = *(const float4*)(x0 + base);
    a.x = m0.x * a.x + m1.x * b.x;
    a.y = m0.y * a.y + m1.y * b.y;
    a.z = m0.z * a.z + m1.z * b.z;
    a.w = m0.w * a.w + m1.w * b.w;
  }
  float ss = a.x * a.x + a.y * a.y + a.z * a.z + a.w * a.w;
  float tot = blk_sum256(ss, sbuf);
  float rn = rsqrtf(tot * (1.0f / DIM) + EPSF);
  if (NP > 0 || MIX) *(float4*)(x + base) = a;
  u16x4 q;
  q[0] = f2b(a.x * rn); q[1] = f2b(a.y * rn); q[2] = f2b(a.z * rn); q[3] = f2b(a.w * rn);
  *(u16x4*)(xn + base) = q;
}

// ---------------- GEMM: C(MxN) = A(MxK) @ Bt(NxK)^T, bf16 in, f32 acc ----------------
// EPI 1: partial store Cb[z][row][col] = bf16(acc) (folded later in norm_k)
// EPI 2: Cb = bf16(relu(acc)^2)
template <int EPI, int BN>
__global__ __launch_bounds__(256, (BN == 64 ? 3 : 2)) void gemm_bt(
    const u16* __restrict__ A, const u16* __restrict__ Bt,
    u16* __restrict__ Cb,
    int N, int K, int kpn) {
  constexpr int MF = (BN == 128) ? 4 : 2;
  constexpr int ASZ = 128 * 64;   // u16 per buffer
  constexpr int BSZ = BN * 64;
  constexpr int NLD = 4 + BN / 32;
  __shared__ u16 As[2 * ASZ];
  __shared__ u16 Bs[2 * BSZ];
  int tid = threadIdx.x;
  int wid = tid >> 6, lane = tid & 63;
  int g = lane >> 4, c = lane & 15;
  int row0 = blockIdx.y << 7, col0 = blockIdx.x * BN;
  int kbase = blockIdx.z * kpn;
  int wr = (BN == 128) ? ((wid >> 1) << 6) : (wid << 5);
  int wc = (BN == 128) ? ((wid & 1) << 6) : 0;
  f32x4 acc[MF][4] = {};

  int sr = lane >> 3;      // row within 8-row segment
  int kb = lane & 7;       // 16B block within row
  const u16* srcA[4];
  int ldsA[4];
#pragma unroll
  for (int i = 0; i < 4; ++i) {
    int s = (wid << 2) + i;
    int r = (s << 3) + sr;
    srcA[i] = A + (size_t)(row0 + r) * K + kbase + ((kb ^ (r & 7)) << 3);
    ldsA[i] = s << 9;
  }
  const u16* srcB[BN / 32];
  int ldsB[BN / 32];
#pragma unroll
  for (int i = 0; i < BN / 32; ++i) {
    int s = wid * (BN / 32) + i;
    int r = (s << 3) + sr;
    srcB[i] = Bt + (size_t)(col0 + r) * K + kbase + ((kb ^ (r & 7)) << 3);
    ldsB[i] = s << 9;
  }

#pragma unroll
  for (int i = 0; i < 4; ++i) gload16(srcA[i], As + ldsA[i]);
#pragma unroll
  for (int i = 0; i < BN / 32; ++i) gload16(srcB[i], Bs + ldsB[i]);

  int nk = kpn >> 6;
  for (int t = 0; t < nk; ++t) {
    int cur = t & 1;
    if (t + 1 < nk) {
      int nxt = cur ^ 1;
      int ko = (t + 1) << 6;
#pragma unroll
      for (int i = 0; i < 4; ++i) gload16(srcA[i] + ko, As + nxt * ASZ + ldsA[i]);
#pragma unroll
      for (int i = 0; i < BN / 32; ++i) gload16(srcB[i] + ko, Bs + nxt * BSZ + ldsB[i]);
      if constexpr (NLD == 6) asm volatile("s_waitcnt vmcnt(6)" ::: "memory");
      else asm volatile("s_waitcnt vmcnt(8)" ::: "memory");
    } else {
      asm volatile("s_waitcnt vmcnt(0)" ::: "memory");
    }
    __builtin_amdgcn_s_barrier();
    MEMFENCE;
    const u16* ab = As + cur * ASZ;
    const u16* bb = Bs + cur * BSZ;
#pragma unroll
    for (int ks = 0; ks < 2; ++ks) {
      bf16x8 af[MF], bfr[4];
#pragma unroll
      for (int m = 0; m < MF; ++m) {
        int r = wr + m * 16 + c;
        int kbs = ((ks << 2) + g) ^ (r & 7);
        af[m] = *(const bf16x8*)(ab + r * 64 + (kbs << 3));
      }
#pragma unroll
      for (int n = 0; n < 4; ++n) {
        int r = wc + n * 16 + c;
        int kbs = ((ks << 2) + g) ^ (r & 7);
        bfr[n] = *(const bf16x8*)(bb + r * 64 + (kbs << 3));
      }
      __builtin_amdgcn_s_setprio(1);
#pragma unroll
      for (int m = 0; m < MF; ++m)
#pragma unroll
        for (int n = 0; n < 4; ++n)
          acc[m][n] = __builtin_amdgcn_mfma_f32_16x16x32_bf16(af[m], bfr[n], acc[m][n], 0, 0, 0);
      __builtin_amdgcn_s_setprio(0);
    }
    MEMFENCE;
    __builtin_amdgcn_s_barrier();
  }

  size_t zoff = (size_t)blockIdx.z * PSTRIDE;
#pragma unroll
  for (int m = 0; m < MF; ++m) {
#pragma unroll
    for (int n = 0; n < 4; ++n) {
      int gcol = col0 + wc + n * 16 + c;
#pragma unroll
      for (int j = 0; j < 4; ++j) {
        int grow = row0 + wr + m * 16 + g * 4 + j;
        float v = acc[m][n][j];
        if (EPI == 1) {
          Cb[zoff + (size_t)grow * N + gcol] = f2b(v);
        } else if (EPI == 2) {
          float r = v > 0.f ? v : 0.f;
          Cb[(size_t)grow * N + gcol] = f2b(r * r);
        }
      }
    }
  }
}

// ---------------- LM-head GEMM: 256x256 tile, BK=64, 8-phase interleaved schedule ---------
// (r18-proven 209us: ds_read frags FIRST, then one half-tile stage, then MFMA.)
// Calendar: P0:A-h0(t1) P1:A-h1(t1) P2:B-h0(t0+2) P3:B-h1(t0+2) P4:A-h0(t0+2) P5:A-h1(t0+2)
// P6:B-h0(t1+2) P7:B-h1(t1+2); vmcnt(4) at P0/P4, vmcnt(0) at last iter's P4.
__global__ __launch_bounds__(512, 2) void gemm_lmhead(
    const u16* __restrict__ A, const u16* __restrict__ Bt,
    const int* __restrict__ tgt, float* __restrict__ pM, float* __restrict__ pS,
    float* __restrict__ loTgt) {
  constexpr int K = 1024;
  constexpr int TSZ = 256 * 64;           // u16 per tile buffer (32 KB)
  __shared__ u16 As[2 * TSZ];
  __shared__ u16 Bs[2 * TSZ];
  int tid = threadIdx.x;
  int wid = tid >> 6, lane = tid & 63;
  int wm = wid >> 2, wn = wid & 3;
  int g = lane >> 4, c = lane & 15;
  int bid = blockIdx.x;
  int swz = ((bid & 7) << 7) + (bid >> 3);
  int colb = swz >> 3, rowb = swz & 7;
  int row0 = rowb << 8, col0 = colb << 8;
  f32x4 acc[8][4] = {};

  int sr = lane >> 3, kb = lane & 7;
  const u16* srcA[2][2];
  const u16* srcB[2][2];
  int ldsOff[2][2];
#pragma unroll
  for (int h = 0; h < 2; ++h)
#pragma unroll
    for (int i = 0; i < 2; ++i) {
      int s = (h << 4) + (wid << 1) + i;
      int r = (s << 3) + sr;
      srcA[h][i] = A + (size_t)(row0 + r) * K + ((kb ^ (r & 7)) << 3);
      srcB[h][i] = Bt + (size_t)(col0 + r) * K + ((kb ^ (r & 7)) << 3);
      ldsOff[h][i] = s << 9;
    }

  auto stageA = [&](int T, int h) {
    int ko = T << 6;
    int bo = (T & 1) * TSZ;
#pragma unroll
    for (int i = 0; i < 2; ++i) gload16(srcA[h][i] + ko, As + bo + ldsOff[h][i]);
  };
  auto stageB = [&](int T, int h) {
    int ko = T << 6;
    int bo = (T & 1) * TSZ;
#pragma unroll
    for (int i = 0; i < 2; ++i) gload16(srcB[h][i] + ko, Bs + bo + ldsOff[h][i]);
  };

  // prologue: B(0), A(0), B(1) — 12 loads/thread; P0's vmcnt(4) waits through A(0)
  stageB(0, 0); stageB(0, 1);
  stageA(0, 0); stageA(0, 1);
  stageB(1, 0); stageB(1, 1);

  bf16x8 bfr[4][2];
  for (int kt2 = 0; kt2 < 16; kt2 += 2) {
#pragma unroll
    for (int p = 0; p < 8; ++p) {
      int tt = p >> 2;           // tile within pair (== LDS buffer, kt2 even)
      int q = p & 3;             // output quadrant (m-frags 2q, 2q+1)
      int bo = tt * TSZ;
      if (p == 0) {
        asm volatile("s_waitcnt vmcnt(4)" ::: "memory");
      } else if (p == 4) {
        if (kt2 == 14) { asm volatile("s_waitcnt vmcnt(0)" ::: "memory"); }
        else           { asm volatile("s_waitcnt vmcnt(4)" ::: "memory"); }
      }
      __builtin_amdgcn_s_barrier();
      MEMFENCE;
      if (q == 0) {
#pragma unroll
        for (int nf = 0; nf < 4; ++nf) {
          int r = (wn << 6) + nf * 16 + c;
#pragma unroll
          for (int ks = 0; ks < 2; ++ks) {
            int kbs = ((ks << 2) + g) ^ (r & 7);
            bfr[nf][ks] = *(const bf16x8*)(Bs + bo + r * 64 + (kbs << 3));
          }
        }
      }
      bf16x8 af[2][2];
#pragma unroll
      for (int mi = 0; mi < 2; ++mi) {
        int r = (wm << 7) + ((q << 1) + mi) * 16 + c;
#pragma unroll
        for (int ks = 0; ks < 2; ++ks) {
          int kbs = ((ks << 2) + g) ^ (r & 7);
          af[mi][ks] = *(const bf16x8*)(As + bo + r * 64 + (kbs << 3));
        }
      }
      // one half-tile stage per phase (calendar above)
      if (p == 0)      { stageA(kt2 + 1, 0); }
      else if (p == 1) { stageA(kt2 + 1, 1); }
      else if (p == 2) { if (kt2 + 2 < 16) stageB(kt2 + 2, 0); }
      else if (p == 3) { if (kt2 + 2 < 16) stageB(kt2 + 2, 1); }
      else if (p == 4) { if (kt2 + 2 < 16) stageA(kt2 + 2, 0); }
      else if (p == 5) { if (kt2 + 2 < 16) stageA(kt2 + 2, 1); }
      else if (p == 6) { if (kt2 + 3 < 16) stageB(kt2 + 3, 0); }
      else             { if (kt2 + 3 < 16) stageB(kt2 + 3, 1); }
      MEMFENCE;
      __builtin_amdgcn_s_barrier();
      __builtin_amdgcn_s_setprio(1);
#pragma unroll
      for (int ks = 0; ks < 2; ++ks)
#pragma unroll
        for (int mi = 0; mi < 2; ++mi)
#pragma unroll
          for (int nf = 0; nf < 4; ++nf)
            acc[(q << 1) + mi][nf] = __builtin_amdgcn_mfma_f32_16x16x32_bf16(
                af[mi][ks], bfr[nf][ks], acc[(q << 1) + mi][nf], 0, 0, 0);
      __builtin_amdgcn_s_setprio(0);
    }
  }

  int cb = (col0 >> 6) + wn;
#pragma unroll
  for (int mf = 0; mf < 8; ++mf) {
#pragma unroll
    for (int j = 0; j < 4; ++j) {
      int grow = row0 + (wm << 7) + mf * 16 + g * 4 + j;
      int tg = tgt[grow];
      float sv[4];
      float mx = -3.0e38f;
#pragma unroll
      for (int nf = 0; nf < 4; ++nf) {
        float a = acc[mf][nf][j] * (1.0f / SCAP);
        a = fminf(fmaxf(a, -15.f), 15.f);
        float e = __expf(2.0f * a);
        float tt = SCAP * (e - 1.0f) / (e + 1.0f);
        sv[nf] = tt;
        mx = fmaxf(mx, tt);
        int gcol = col0 + (wn << 6) + nf * 16 + c;
        if (gcol == tg) loTgt[grow] = tt;
      }
      mx = fmaxf(mx, __shfl_xor(mx, 1, 64));
      mx = fmaxf(mx, __shfl_xor(mx, 2, 64));
      mx = fmaxf(mx, __shfl_xor(mx, 4, 64));
      mx = fmaxf(mx, __shfl_xor(mx, 8, 64));
      float s = 0.f;
#pragma unroll
      for (int nf = 0; nf < 4; ++nf) s += __expf(sv[nf] - mx);
      s += __shfl_xor(s, 1, 64);
      s += __shfl_xor(s, 2, 64);
      s += __shfl_xor(s, 4, 64);
      s += __shfl_xor(s, 8, 64);
      if (c == 0) {
        pM[(size_t)grow * NCB + cb] = mx;
        pS[(size_t)grow * NCB + cb] = s;
      }
    }
  }
}

// ---------------- fused QKV GEMM: epilogue does q/k rms+rope+qg and v(+ve)->vT ----------------
__global__ __launch_bounds__(256, 3) void gemm_qkv(
    const u16* __restrict__ A, const u16* __restrict__ Bt,
    const float* __restrict__ qg_l, const float* __restrict__ rc, const float* __restrict__ rs,
    const float* __restrict__ ve, const int* __restrict__ ids, int vb,
    u16* __restrict__ qB, u16* __restrict__ kB, u16* __restrict__ vT) {
  constexpr int K = 1024;
  constexpr int ASZ = 128 * 64;
  constexpr int BSZ = 64 * 64;
  __shared__ u16 As[2 * ASZ];
  __shared__ u16 Bs[2 * BSZ];
  int tid = threadIdx.x;
  int wid = tid >> 6, lane = tid & 63;
  int g = lane >> 4, c = lane & 15;
  int bx = blockIdx.x;
  int row0 = blockIdx.y << 7, col0 = bx << 6;
  f32x4 acc[2][4] = {};

  int sr = lane >> 3, kb = lane & 7;
  const u16* srcA[4];
  int ldsA[4];
#pragma unroll
  for (int i = 0; i < 4; ++i) {
    int s = (wid << 2) + i;
    int r = (s << 3) + sr;
    srcA[i] = A + (size_t)(row0 + r) * K + ((kb ^ (r & 7)) << 3);
    ldsA[i] = s << 9;
  }
  const u16* srcB[2];
  int ldsB[2];
#pragma unroll
  for (int i = 0; i < 2; ++i) {
    int s = (wid << 1) + i;
    int r = (s << 3) + sr;
    srcB[i] = Bt + (size_t)(col0 + r) * K + ((kb ^ (r & 7)) << 3);
    ldsB[i] = s << 9;
  }

#pragma unroll
  for (int i = 0; i < 4; ++i) gload16(srcA[i], As + ldsA[i]);
#pragma unroll
  for (int i = 0; i < 2; ++i) gload16(srcB[i], Bs + ldsB[i]);

  for (int t = 0; t < 16; ++t) {
    int cur = t & 1;
    if (t + 1 < 16) {
      int nxt = cur ^ 1;
      int ko = (t + 1) << 6;
#pragma unroll
      for (int i = 0; i < 4; ++i) gload16(srcA[i] + ko, As + nxt * ASZ + ldsA[i]);
#pragma unroll
      for (int i = 0; i < 2; ++i) gload16(srcB[i] + ko, Bs + nxt * BSZ + ldsB[i]);
      asm volatile("s_waitcnt vmcnt(6)" ::: "memory");
    } else {
      asm volatile("s_waitcnt vmcnt(0)" ::: "memory");
    }
    __builtin_amdgcn_s_barrier();
    MEMFENCE;
    const u16* ab = As + cur * ASZ;
    const u16* bb = Bs + cur * BSZ;
#pragma unroll
    for (int ks = 0; ks < 2; ++ks) {
      bf16x8 af[2], bfr[4];
#pragma unroll
      for (int m = 0; m < 2; ++m) {
        int r = (wid << 5) + m * 16 + c;
        int kbs = ((ks << 2) + g) ^ (r & 7);
        af[m] = *(const bf16x8*)(ab + r * 64 + (kbs << 3));
      }
#pragma unroll
      for (int n = 0; n < 4; ++n) {
        int r = n * 16 + c;
        int kbs = ((ks << 2) + g) ^ (r & 7);
        bfr[n] = *(const bf16x8*)(bb + r * 64 + (kbs << 3));
      }
      __builtin_amdgcn_s_setprio(1);
#pragma unroll
      for (int m = 0; m < 2; ++m)
#pragma unroll
        for (int n = 0; n < 4; ++n)
          acc[m][n] = __builtin_amdgcn_mfma_f32_16x16x32_bf16(af[m], bfr[n], acc[m][n], 0, 0, 0);
      __builtin_amdgcn_s_setprio(0);
    }
    MEMFENCE;
    __builtin_amdgcn_s_barrier();
  }

  int b = row0 >> 10;
  if (bx < 24) {
    bool isq = (bx < 16);
    int h = isq ? bx : bx - 16;
    float gmul = isq ? qg_l[h] * 0.125f : 1.0f;
    u16* hb = isq ? (qB + ((size_t)(b * NHD + h)) * T_SEQ * HDIM)
                  : (kB + ((size_t)(b * NKVH + h)) * T_SEQ * HDIM);
#pragma unroll
    for (int m = 0; m < 2; ++m) {
#pragma unroll
      for (int j = 0; j < 4; ++j) {
        int grow = row0 + (wid << 5) + m * 16 + g * 4 + j;
        int t = grow & (T_SEQ - 1);
        float vv[4];
        float ss = 0.f;
#pragma unroll
        for (int n = 0; n < 4; ++n) { vv[n] = acc[m][n][j]; ss += vv[n] * vv[n]; }
        ss += __shfl_xor(ss, 1, 64);
        ss += __shfl_xor(ss, 2, 64);
        ss += __shfl_xor(ss, 4, 64);
        ss += __shfl_xor(ss, 8, 64);
        float rn = rsqrtf(ss * (1.0f / HDIM) + EPSF);
#pragma unroll
        for (int n = 0; n < 4; ++n) vv[n] *= rn;
        float c0 = rc[t * 32 + c], s0 = rs[t * 32 + c];
        float c1 = rc[t * 32 + 16 + c], s1 = rs[t * 32 + 16 + c];
        float o0 = vv[0] * c0 + vv[2] * s0;
        float o1 = vv[1] * c1 + vv[3] * s1;
        float o2 = vv[2] * c0 - vv[0] * s0;
        float o3 = vv[3] * c1 - vv[1] * s1;
        u16* dst = hb + (size_t)t * HDIM;
        dst[c] = f2b(o0 * gmul);
        dst[16 + c] = f2b(o1 * gmul);
        dst[32 + c] = f2b(o2 * gmul);
        dst[48 + c] = f2b(o3 * gmul);
      }
    }
  } else {
    int kh = bx - 24;
#pragma unroll
    for (int m = 0; m < 2; ++m) {
#pragma unroll
      for (int j = 0; j < 4; ++j) {
        int grow = row0 + (wid << 5) + m * 16 + g * 4 + j;
        int lr = (wid << 5) + m * 16 + g * 4 + j;
        int id = ids[grow];
        const float* vl = ve + ((size_t)vb * VOC + id) * KVD + kh * HDIM;
#pragma unroll
        for (int n = 0; n < 4; ++n)
          As[lr * 72 + n * 16 + c] = f2b(acc[m][n][j] + vl[n * 16 + c]);
      }
    }
    __syncthreads();
    int hd = tid & 63, seg = tid >> 6;
    int t0 = (row0 & (T_SEQ - 1)) + seg * 32;
    u16* dst = vT + (((size_t)(b * NKVH + kh)) * HDIM + hd) * T_SEQ + t0;
#pragma unroll
    for (int i = 0; i < 32; i += 8) {
      u16x8 o;
#pragma unroll
      for (int e = 0; e < 8; ++e) o[e] = As[(seg * 32 + i + e) * 72 + hd];
      *(u16x8*)(dst + i) = o;
    }
  }
}

// ---------------- flash attention: static-max softmax, ones rowsum, 2-deep KV prefetch ----
// (r15-proven: grid (16, NHD, B), block 128, 32-row strips paired (s, 31-s).)
__global__ __launch_bounds__(128) void attn_kernel(const u16* __restrict__ qB,
    const u16* __restrict__ kB, const u16* __restrict__ vT, const float* __restrict__ qg_l,
    u16* __restrict__ attout) {
  __shared__ u16 plds[2][32 * 76];
  int b = blockIdx.z, h = blockIdx.y;
  int kh = h >> 1;
  int wid = threadIdx.x >> 6, lane = threadIdx.x & 63;
  int g = lane >> 4, c = lane & 15;
  int strip = wid ? (31 - (int)blockIdx.x) : (int)blockIdx.x;
  int qr0 = strip << 5;
  const u16* qptr = qB + ((size_t)(b * NHD + h)) * T_SEQ * HDIM;
  const u16* kptr = kB + ((size_t)(b * NKVH + kh)) * T_SEQ * HDIM;
  const u16* vptr = vT + ((size_t)(b * NKVH + kh)) * HDIM * T_SEQ;
  u16* pw = plds[wid];
  float Mh = fabsf(qg_l[h]) * 8.0f;

  bf16x8 aq[2][2];
#pragma unroll
  for (int m = 0; m < 2; ++m)
#pragma unroll
    for (int ks = 0; ks < 2; ++ks)
      aq[m][ks] = *(const bf16x8*)(qptr + (qr0 + m * 16 + c) * HDIM + ks * 32 + g * 8);

  bf16x8 vone;
#pragma unroll
  for (int e = 0; e < 8; ++e) vone[e] = (short)0x3F80;

  f32x4 oacc[2][4] = {};
  f32x4 lacc[2] = {};

  bf16x8 kR0[4][2], vR0[4][2], kR1[4][2], vR1[4][2];

  auto LOADKV = [&](bf16x8 (&bk)[4][2], bf16x8 (&bv)[4][2], int kv0) {
#pragma unroll
    for (int n = 0; n < 4; ++n)
#pragma unroll
      for (int ks = 0; ks < 2; ++ks) {
        bk[n][ks] = *(const bf16x8*)(kptr + (kv0 + n * 16 + c) * HDIM + ks * 32 + g * 8);
        bv[n][ks] = *(const bf16x8*)(vptr + (n * 16 + c) * T_SEQ + kv0 + ks * 32 + g * 8);
      }
  };

  auto BODY = [&](bf16x8 (&bk)[4][2], bf16x8 (&bv)[4][2], int kv0) {
    f32x4 sc[2][4] = {};
#pragma unroll
    for (int ks = 0; ks < 2; ++ks)
#pragma unroll
      for (int m = 0; m < 2; ++m)
#pragma unroll
        for (int n = 0; n < 4; ++n)
          sc[m][n] = __builtin_amdgcn_mfma_f32_16x16x32_bf16(aq[m][ks], bk[n][ks], sc[m][n], 0, 0, 0);
    bool maskT = (kv0 + 64 > qr0);
#pragma unroll
    for (int m = 0; m < 2; ++m) {
#pragma unroll
      for (int j = 0; j < 4; ++j) {
        int row = qr0 + m * 16 + g * 4 + j;
        float p0 = __expf(sc[m][0][j] - Mh);
        float p1 = __expf(sc[m][1][j] - Mh);
        float p2 = __expf(sc[m][2][j] - Mh);
        float p3 = __expf(sc[m][3][j] - Mh);
        if (maskT) {
          if (kv0 + c > row) p0 = 0.f;
          if (kv0 + 16 + c > row) p1 = 0.f;
          if (kv0 + 32 + c > row) p2 = 0.f;
          if (kv0 + 48 + c > row) p3 = 0.f;
        }
        int pr = m * 16 + g * 4 + j;
        pw[pr * 76 + c] = f2b(p0);
        pw[pr * 76 + 16 + c] = f2b(p1);
        pw[pr * 76 + 32 + c] = f2b(p2);
        pw[pr * 76 + 48 + c] = f2b(p3);
      }
    }
    MEMFENCE;
    bf16x8 ap[2][2];
#pragma unroll
    for (int m = 0; m < 2; ++m)
#pragma unroll
      for (int ks = 0; ks < 2; ++ks) {
        u16x8 tmp = *(const u16x8*)(pw + (m * 16 + c) * 76 + ks * 32 + g * 8);
        __builtin_memcpy(&ap[m][ks], &tmp, 16);
      }
#pragma unroll
    for (int ks = 0; ks < 2; ++ks) {
#pragma unroll
      for (int m = 0; m < 2; ++m) {
#pragma unroll
        for (int n = 0; n < 4; ++n)
          oacc[m][n] = __builtin_amdgcn_mfma_f32_16x16x32_bf16(ap[m][ks], bv[n][ks], oacc[m][n], 0, 0, 0);
        lacc[m] = __builtin_amdgcn_mfma_f32_16x16x32_bf16(ap[m][ks], vone, lacc[m], 0, 0, 0);
      }
    }
  };

  LOADKV(kR0, vR0, 0);
  int kv0 = 0;
  while (true) {
    if (kv0 + 64 <= qr0) LOADKV(kR1, vR1, kv0 + 64);
    BODY(kR0, vR0, kv0);
    kv0 += 64;
    if (kv0 > qr0) break;
    if (kv0 + 64 <= qr0) LOADKV(kR0, vR0, kv0 + 64);
    BODY(kR1, vR1, kv0);
    kv0 += 64;
    if (kv0 > qr0) break;
  }

#pragma unroll
  for (int m = 0; m < 2; ++m) {
#pragma unroll
    for (int j = 0; j < 4; ++j) {
      float inv = 1.0f / lacc[m][j];
      int trow = qr0 + m * 16 + g * 4 + j;
      u16* orow = attout + ((size_t)(b * T_SEQ + trow)) * DIM + h * HDIM;
#pragma unroll
      for (int n = 0; n < 4; ++n)
        orow[n * 16 + c] = f2b(oacc[m][n][j] * inv);
    }
  }
}

// ---------------- LM-head merge: combine 512 per-colblock partials -> nll per token ----------
__global__ __launch_bounds__(256) void lse_merge(const float* __restrict__ pM,
    const float* __restrict__ pS, const float* __restrict__ loTgt, float* __restrict__ nll) {
  __shared__ float sbuf[4];
  int tok = blockIdx.x, tid = threadIdx.x;
  int wid = tid >> 6, lane = tid & 63;
  const float* rm = pM + (size_t)tok * NCB;
  const float* rs = pS + (size_t)tok * NCB;
  float m0 = rm[tid], m1 = rm[tid + 256];
  float mx = fmaxf(m0, m1);
#pragma unroll
  for (int o = 32; o; o >>= 1) mx = fmaxf(mx, __shfl_xor(mx, o, 64));
  if (lane == 0) sbuf[wid] = mx;
  __syncthreads();
  float M = fmaxf(fmaxf(sbuf[0], sbuf[1]), fmaxf(sbuf[2], sbuf[3]));
  __syncthreads();
  float s = rs[tid] * __expf(m0 - M) + rs[tid + 256] * __expf(m1 - M);
  float S = blk_sum256(s, sbuf);
  if (tid == 0) nll[tok] = logf(S) + M - loTgt[tok];
}

__global__ __launch_bounds__(256) void loss_final(const float* __restrict__ nll,
    float* __restrict__ out) {
  __shared__ float sbuf[4];
  int tid = threadIdx.x;
  float acc = 0.f;
  for (int i = tid; i < NTOK; i += 256) acc += nll[i];
  float tot = blk_sum256(acc, sbuf);
  if (tid == 0) out[0] = tot * (1.0f / NTOK);
}

// ---------------- host ----------------
extern "C" void kernel_launch(void* const* d_in, const int* in_sizes, int n_in,
                              void* d_out, int out_size, void* d_ws, size_t ws_size,
                              hipStream_t stream) {
  (void)in_sizes; (void)n_in; (void)out_size; (void)ws_size;
  const int* ids = (const int*)d_in[0];
  const int* tgt = (const int*)d_in[1];
  const float* emb = (const float*)d_in[2];
  const float* bg_embed = (const float*)d_in[3];
  const float* bg_proj = (const float*)d_in[4];
  const float* bg_scale = (const float*)d_in[5];
  const float* ve = (const float*)d_in[6];
  const float* Wq = (const float*)d_in[7];
  const float* Wk = (const float*)d_in[8];
  const float* Wv = (const float*)d_in[9];
  const float* Wo = (const float*)d_in[10];
  const float* qg = (const float*)d_in[11];
  const float* a_s = (const float*)d_in[12];
  const float* m_s = (const float*)d_in[13];
  const float* mix = (const float*)d_in[14];
  const float* Wfc = (const float*)d_in[15];
  const float* Wpr = (const float*)d_in[16];

  char* w = (char*)d_ws;
  auto alloc = [&](size_t bytes) {
    char* p = w;
    w += (bytes + 255) & ~(size_t)255;
    return p;
  };
  u16* WqkvT = (u16*)alloc(6ull * 2048 * 1024 * 2);
  u16* WoT   = (u16*)alloc(6ull * 1024 * 1024 * 2);
  u16* WfcT  = (u16*)alloc(6ull * 3072 * 1024 * 2);
  u16* WprT  = (u16*)alloc(6ull * 1024 * 3072 * 2);
  u16* embB  = (u16*)alloc((size_t)VOC * DIM * 2);
  float* x   = (float*)alloc((size_t)NTOK * DIM * 4);
  float* x0  = (float*)alloc((size_t)NTOK * DIM * 4);
  u16* xn    = (u16*)alloc((size_t)NTOK * DIM * 2);
  u16* qBuf  = (u16*)alloc((size_t)NTOK * DIM * 2);
  u16* kBuf  = (u16*)alloc((size_t)NTOK * KVD * 2);
  u16* vTb   = (u16*)alloc((size_t)NTOK * KVD * 2);
  u16* attout = (u16*)alloc((size_t)NTOK * DIM * 2);
  u16* xmlp  = (u16*)alloc((size_t)NTOK * DIM * 2);
  u16* hmid  = (u16*)alloc((size_t)NTOK * MLPD * 2);
  u16* pparts = (u16*)alloc(3 * PSTRIDE * 2);
  float* rc  = (float*)alloc((size_t)T_SEQ * 32 * 4);
  float* rs  = (float*)alloc((size_t)T_SEQ * 32 * 4);
  float* pM  = (float*)alloc((size_t)NTOK * NCB * 4);
  float* pS  = (float*)alloc((size_t)NTOK * NCB * 4);
  float* loTgt = (float*)alloc(NTOK * 4);
  float* nll = (float*)alloc(NTOK * 4);

  prep_all<<<73856, 256, 0, stream>>>(Wq, Wk, Wv, Wo, Wfc, Wpr, emb,
      WqkvT, WoT, WfcT, WprT, embB, rc, rs,
      ids, bg_embed, bg_proj, bg_scale, mix, x, x0, xn);

  int lprev = 0;
  for (int step = 0; step < 12; ++step) {
    int l = step % 6;
    if (step > 0)
      norm_k<3, 1><<<NTOK, 256, 0, stream>>>(x, pparts, m_s + lprev * DIM, mix + l * 2048, x0, xn);
    gemm_qkv<<<dim3(32, 16), 256, 0, stream>>>(xn, WqkvT + (size_t)l * 2048 * 1024,
        qg + l * 16, rc, rs, ve, ids, step % 5, qBuf, kBuf, vTb);
    attn_kernel<<<dim3(16, 16, 2), 128, 0, stream>>>(qBuf, kBuf, vTb, qg + l * 16, attout);
    gemm_bt<1, 64><<<dim3(16, 16, 2), 256, 0, stream>>>(attout, WoT + (size_t)l * 1024 * 1024,
        pparts, 1024, 1024, 512);
    norm_k<2, 0><<<NTOK, 256, 0, stream>>>(x, pparts, a_s + l * DIM, nullptr, nullptr, xmlp);
    gemm_bt<2, 64><<<dim3(48, 16, 1), 256, 0, stream>>>(xmlp, WfcT + (size_t)l * 3072 * 1024,
        hmid, 3072, 1024, 1024);
    gemm_bt<1, 64><<<dim3(16, 16, 3), 256, 0, stream>>>(hmid, WprT + (size_t)l * 1024 * 3072,
        pparts, 1024, 3072, 1024);
    lprev = l;
  }

  norm_k<3, 0><<<NTOK, 256, 0, stream>>>(x, pparts, m_s + lprev * DIM, nullptr, nullptr, xn);
  gemm_lmhead<<<1024, 512, 0, stream>>>(xn, embB, tgt, pM, pS, loTgt);
  lse_merge<<<NTOK, 256, 0, stream>>>(pM, pS, loTgt, nll);
  loss_final<<<1, 256, 0, stream>>>(nll, (float*)d_out);
}